// Round 3
// baseline (45771.704 us; speedup 1.0000x reference)
//
#include <hip/hip_runtime.h>
#include <cstdint>

typedef __attribute__((ext_vector_type(8))) __bf16 bf16x8;
typedef __attribute__((ext_vector_type(4))) float f32x4;
typedef __attribute__((ext_vector_type(4))) unsigned int uint4v;
typedef __attribute__((ext_vector_type(4))) float float4v;

__device__ __forceinline__ unsigned short f2bf(float x){
  union { float f; unsigned u; } v; v.f = x;
  unsigned r = v.u + 0x7FFFu + ((v.u >> 16) & 1u);
  return (unsigned short)(r >> 16);
}
__device__ __forceinline__ float bf2f(unsigned short h){
  union { unsigned u; float f; } v; v.u = ((unsigned)h) << 16;
  return v.f;
}
__device__ __forceinline__ float bflo(unsigned u){
  union { unsigned x; float f; } v; v.x = u << 16; return v.f;
}
__device__ __forceinline__ float bfhi(unsigned u){
  union { unsigned x; float f; } v; v.x = u & 0xFFFF0000u; return v.f;
}
__device__ __forceinline__ f32x4 MFMA16(bf16x8 a, bf16x8 b, f32x4 c){
  return __builtin_amdgcn_mfma_f32_16x16x32_bf16(a, b, c, 0, 0, 0);
}

// ---------------- prep: bf16 conversions + transposes + GRU weight frag layout ----
// wfrag layout: [mg(6)=mat*3+gate][ct(16)][kk(8)][lane(64)][e(8)] bf16
//   element = W_mat[n*256+k], n = gate*256 + ct*16 + (lane&15), k = kk*32 + (lane>>4)*8 + e
__global__ __launch_bounds__(256) void prep_k(
    const float* __restrict__ wih, const float* __restrict__ whh,
    const float* __restrict__ wl, const float* __restrict__ wr,
    const float* __restrict__ bl, const float* __restrict__ br,
    const float* __restrict__ fcw,
    unsigned short* __restrict__ wfrag,
    unsigned short* __restrict__ wlrT, unsigned short* __restrict__ fcwT,
    float* __restrict__ blbr){
  int i = blockIdx.x*256 + threadIdx.x;
  if (i < 393216){
    int mg = i >> 16;            // 0..5 = mat*3+gate
    int rem = i & 65535;
    int ct = rem >> 12;
    int r3 = rem & 4095;
    int kk = r3 >> 9;
    int r4 = r3 & 511;
    int l = r4 >> 3, e = r4 & 7;
    int mat = mg / 3, g = mg - 3*(mg/3);
    int n = g*256 + ct*16 + (l & 15);
    int k = kk*32 + (l >> 4)*8 + e;
    float v = mat ? whh[n*256 + k] : wih[n*256 + k];
    wfrag[i] = f2bf(v);
    return;
  }
  i -= 393216;
  if (i < 655360){
    int n = i >> 8, k = i & 255;
    float v = (n < 1280) ? wl[k*1280 + n] : wr[k*1280 + (n-1280)];
    wlrT[i] = f2bf(v); return;
  }
  i -= 655360;
  if (i < 802816){
    int n = i / 3136, k = i - n*3136;
    fcwT[i] = f2bf(fcw[k*256 + n]); return;
  }
  i -= 802816;
  if (i < 2560){
    blbr[i] = (i < 1280) ? bl[i] : br[i-1280];
  }
}

// ---------------- conv1: [256,3,84,84] -> bf16 [256,32,20,20], s=4 k=8, relu ----
__global__ __launch_bounds__(256) void conv1_k(const float* __restrict__ in,
              const float* __restrict__ w, const float* __restrict__ bias,
              unsigned short* __restrict__ out){
  __shared__ float in_s[3][24][84];
  __shared__ float w_s[32][3][8][8];
  __shared__ float b_s[32];
  int bid = blockIdx.x; int b = bid >> 2, q = bid & 3;
  int t = threadIdx.x;
  for (int idx = t; idx < 3*24*84; idx += 256){
    int ic = idx / (24*84); int rem = idx - ic*(24*84);
    int iy = rem / 84, ix = rem - iy*84;
    in_s[ic][iy][ix] = in[((size_t)(b*3+ic)*84 + (q*20 + iy))*84 + ix];
  }
  for (int idx = t; idx < 32*192; idx += 256) ((float*)w_s)[idx] = w[idx];
  if (t < 32) b_s[t] = bias[t];
  __syncthreads();
  for (int p = t; p < 800; p += 256){
    int oc = p / 25; int rem = p - oc*25;
    int oy = rem / 5, og = rem - oy*5;
    float a0=b_s[oc],a1=b_s[oc],a2=b_s[oc],a3=b_s[oc];
    #pragma unroll
    for (int ic=0;ic<3;ic++){
      #pragma unroll
      for (int ky=0;ky<8;ky++){
        const float* row = &in_s[ic][oy*4+ky][og*16];
        float s[20];
        #pragma unroll
        for (int cc=0;cc<20;cc++) s[cc]=row[cc];
        const float* wp = &w_s[oc][ic][ky][0];
        #pragma unroll
        for (int kx=0;kx<8;kx++){
          float wv = wp[kx];
          a0 += s[kx]*wv; a1 += s[4+kx]*wv; a2 += s[8+kx]*wv; a3 += s[12+kx]*wv;
        }
      }
    }
    size_t ob = ((size_t)(b*32+oc)*20 + (q*5+oy))*20 + og*4;
    out[ob+0]=f2bf(fmaxf(a0,0.f)); out[ob+1]=f2bf(fmaxf(a1,0.f));
    out[ob+2]=f2bf(fmaxf(a2,0.f)); out[ob+3]=f2bf(fmaxf(a3,0.f));
  }
}

// ---------------- conv2: bf16 [256,32,20,20] -> bf16 [256,64,9,9], s=2 k=4 ----
__global__ __launch_bounds__(256) void conv2_k(const unsigned short* __restrict__ in,
              const float* __restrict__ w, const float* __restrict__ bias,
              unsigned short* __restrict__ out){
  __shared__ unsigned short in_s[32][20][20];
  __shared__ float w_s[16][32][4][4];
  __shared__ float b_s[16];
  int bid = blockIdx.x; int b = bid >> 2, h = bid & 3;
  int t = threadIdx.x;
  for (int idx = t; idx < 32*400; idx += 256) ((unsigned short*)in_s)[idx] = in[(size_t)b*12800 + idx];
  for (int idx = t; idx < 16*512; idx += 256) ((float*)w_s)[idx] = w[h*8192 + idx];
  if (t < 16) b_s[t] = bias[h*16 + t];
  __syncthreads();
  for (int p = t; p < 432; p += 256){
    int ocl = p / 27; int rem = p - ocl*27;
    int oy = rem / 3, og = rem - oy*3;
    float a0=b_s[ocl],a1=b_s[ocl],a2=b_s[ocl];
    #pragma unroll 4
    for (int ic=0;ic<32;ic++){
      #pragma unroll
      for (int ky=0;ky<4;ky++){
        const unsigned short* row = &in_s[ic][oy*2+ky][og*6];
        float s[8];
        #pragma unroll
        for (int cc=0;cc<8;cc++) s[cc]=bf2f(row[cc]);
        const float* wp = &w_s[ocl][ic][ky][0];
        #pragma unroll
        for (int kx=0;kx<4;kx++){
          float wv = wp[kx];
          a0 += s[kx]*wv; a1 += s[2+kx]*wv; a2 += s[4+kx]*wv;
        }
      }
    }
    size_t ob = ((size_t)(b*64 + h*16+ocl)*9 + oy)*9 + og*3;
    out[ob+0]=f2bf(fmaxf(a0,0.f)); out[ob+1]=f2bf(fmaxf(a1,0.f)); out[ob+2]=f2bf(fmaxf(a2,0.f));
  }
}

// ---------------- conv3: bf16 [256,64,9,9] -> bf16 [256,3136] (flat NCHW), s=1 k=3 ----
__global__ __launch_bounds__(256) void conv3_k(const unsigned short* __restrict__ in,
              const float* __restrict__ w, const float* __restrict__ bias,
              unsigned short* __restrict__ out){
  __shared__ unsigned short in_s[64][9][9];
  __shared__ float w_s[16][64][3][3];
  __shared__ float b_s[16];
  int bid = blockIdx.x; int b = bid >> 2, h = bid & 3;
  int t = threadIdx.x;
  for (int idx = t; idx < 64*81; idx += 256) ((unsigned short*)in_s)[idx] = in[(size_t)b*5184 + idx];
  for (int idx = t; idx < 16*576; idx += 256) ((float*)w_s)[idx] = w[h*9216 + idx];
  if (t < 16) b_s[t] = bias[h*16 + t];
  __syncthreads();
  for (int p = t; p < 224; p += 256){
    int ocl = p / 14; int rem = p - ocl*14;
    int oy = rem >> 1, og = rem & 1;
    int ox0 = og*4; int nx = og ? 3 : 4;
    float a[4]; a[0]=a[1]=a[2]=a[3]=b_s[ocl];
    for (int ic=0;ic<64;ic++){
      #pragma unroll
      for (int ky=0;ky<3;ky++){
        const unsigned short* row = &in_s[ic][oy+ky][ox0];
        float s[6];
        #pragma unroll
        for (int cc=0;cc<6;cc++) s[cc] = (ox0+cc < 9) ? bf2f(row[cc]) : 0.f;
        const float* wp = &w_s[ocl][ic][ky][0];
        #pragma unroll
        for (int kx=0;kx<3;kx++){
          float wv = wp[kx];
          #pragma unroll
          for (int jj=0;jj<4;jj++) a[jj] += s[jj+kx]*wv;
        }
      }
    }
    size_t ob = (size_t)b*3136 + (h*16+ocl)*49 + oy*7 + ox0;
    #pragma unroll
    for (int jj=0;jj<4;jj++) if (jj < nx) out[ob+jj] = f2bf(fmaxf(a[jj],0.f));
  }
}

// ---------------- generic MFMA GEMM: C[m,n] = act(A[m,:]·B[n,:] + bias[n]) ----
__global__ __launch_bounds__(256) void gemm_k(const unsigned short* __restrict__ A,
              const unsigned short* __restrict__ B, const float* __restrict__ bias,
              unsigned short* __restrict__ C, int K, int ldc, int rowmul, int relu, int Nblk){
  __shared__ __align__(16) unsigned short As[64*32];
  __shared__ __align__(16) unsigned short Bs[64*32];
  int bid = blockIdx.x;
  int nb = bid % Nblk, mb = bid / Nblk;
  int t = threadIdx.x;
  int w = t >> 6, l = t & 63, lr = l & 15, lh = l >> 4;
  int sr = t >> 2, sq = t & 3;
  f32x4 acc[4];
  #pragma unroll
  for (int i=0;i<4;i++) acc[i] = (f32x4){0.f,0.f,0.f,0.f};
  int nkk = K >> 5;
  const size_t a_row = (size_t)(mb*64 + sr)*K;
  const size_t b_row = (size_t)(nb*64 + sr)*K;
  for (int kk=0;kk<nkk;kk++){
    uint4v av = *(const uint4v*)&A[a_row + kk*32 + sq*8];
    uint4v bv = *(const uint4v*)&B[b_row + kk*32 + sq*8];
    __syncthreads();
    *(uint4v*)((char*)As + ((sr*64 + sq*16) ^ ((sr&3)<<4))) = av;
    *(uint4v*)((char*)Bs + ((sr*64 + sq*16) ^ ((sr&3)<<4))) = bv;
    __syncthreads();
    int brow = w*16 + lr;
    bf16x8 bfr = *(const bf16x8*)((char*)Bs + ((brow*64 + lh*16) ^ ((brow&3)<<4)));
    #pragma unroll
    for (int mt=0;mt<4;mt++){
      int arow = mt*16 + lr;
      bf16x8 afr = *(const bf16x8*)((char*)As + ((arow*64 + lh*16) ^ ((arow&3)<<4)));
      acc[mt] = MFMA16(afr, bfr, acc[mt]);
    }
  }
  int col = nb*64 + w*16 + lr;
  float bn = bias[col];
  #pragma unroll
  for (int mt=0;mt<4;mt++){
    #pragma unroll
    for (int r=0;r<4;r++){
      int row = mb*64 + mt*16 + lh*4 + r;
      float v = acc[mt][r] + bn;
      if (relu) v = fmaxf(v, 0.f);
      C[(size_t)row*rowmul*ldc + col] = f2bf(v);
    }
  }
}

// ---------------- fused MLP+GRU persistent kernel (v3: 2-pass, no spill) --------
// 192 blocks x 1024 threads (16 waves, 4/SIMD); block owns 32 rows; wave owns 16 h-cols.
__global__ __launch_bounds__(1024, 4) void gru_k(const float* __restrict__ obs,
              const float* __restrict__ mlpw, const float* __restrict__ mlpb,
              const unsigned short* __restrict__ wfrag,
              const float* __restrict__ bih, const float* __restrict__ bhh,
              unsigned short* __restrict__ nemb){
  __shared__ __align__(16) float obs_s[32][16];
  __shared__ __align__(16) unsigned short mlp_s[16*256];
  __shared__ __align__(16) float mlpb_s[256];
  __shared__ __align__(16) unsigned short emb_s[32*256];  // swizzled ^(m&15)<<4
  __shared__ __align__(16) unsigned short hb_s[32*256];   // swizzled ^(m&15)<<4

  const int t = threadIdx.x, blk = blockIdx.x;
  for (int j = t; j < 4096; j += 1024) mlp_s[j] = f2bf(mlpw[j]);
  if (t < 256) mlpb_s[t] = mlpb[t];
  for (int j = t; j < 8192; j += 1024) hb_s[j] = 0;

  const int w = t >> 6, l = t & 63, lr = l & 15, lh = l >> 4;
  const int jcol = w*16 + lr;            // h/gate column this lane produces
  const float bR  = bih[jcol]     + bhh[jcol];
  const float bZ  = bih[256+jcol] + bhh[256+jcol];
  const float bXN = bih[512+jcol];
  const float bHN = bhh[512+jcol];

  // stream bases (mg: 0=ih_r 1=ih_z 2=ih_n 3=hh_r 4=hh_z 5=hh_n)
  const unsigned short* wb = wfrag + w*4096 + l*8;
  const unsigned short* sIR = wb;
  const unsigned short* sIZ = wb + 1*65536;
  const unsigned short* sIN = wb + 2*65536;
  const unsigned short* sHR = wb + 3*65536;
  const unsigned short* sHZ = wb + 4*65536;
  const unsigned short* sHN = wb + 5*65536;

  const int em = t >> 5, en0 = (t & 31) << 3;   // MLP: row, col0 (8 cols/thread)

  const int orow = t >> 4, oc = t & 15;          // obs stage (t<512)
  int rrL = blk*32 + orow; int bL = rrL/24, ndL = 1 + (rrL - bL*24);
  const float* obase = obs + (size_t)(bL*25 + ndL)*800 + oc;

  const int aoff = lr*512 + lh*16;   // A-frag base byte (row=lr)
  const int xr = lr << 4;            // swizzle
  const int jj2 = jcol*2;

  __syncthreads();

  for (int step=0; step<50; step++){
    if (t < 512) obs_s[orow][oc] = obase[step*16];
    __syncthreads();
    // ---- MLP emb: thread -> 8 cols of one row ----
    {
      float acc[8];
      #pragma unroll
      for (int q=0;q<8;q++) acc[q] = mlpb_s[en0+q];
      #pragma unroll
      for (int k=0;k<16;k++){
        float o = obs_s[em][k];
        uint4v wv = *(const uint4v*)&mlp_s[k*256 + en0];
        acc[0] += o*bflo(wv[0]); acc[1] += o*bfhi(wv[0]);
        acc[2] += o*bflo(wv[1]); acc[3] += o*bfhi(wv[1]);
        acc[4] += o*bflo(wv[2]); acc[5] += o*bfhi(wv[2]);
        acc[6] += o*bflo(wv[3]); acc[7] += o*bfhi(wv[3]);
      }
      uint4v pk;
      #pragma unroll
      for (int q=0;q<4;q++){
        float x0 = fmaxf(acc[2*q],0.f), x1 = fmaxf(acc[2*q+1],0.f);
        pk[q] = (unsigned)f2bf(x0) | ((unsigned)f2bf(x1) << 16);
      }
      *(uint4v*)((char*)emb_s + ((em*512 + (en0<<1)) ^ ((em&15)<<4))) = pk;
    }
    __syncthreads();
    // ---- pass A: R,Z (4 streams, dbuf) ----
    f32x4 aR[2], aZ[2], aXN[2], aHN[2];
    aR[0]=(f32x4){0,0,0,0}; aR[1]=(f32x4){0,0,0,0};
    aZ[0]=(f32x4){0,0,0,0}; aZ[1]=(f32x4){0,0,0,0};
    {
      bf16x8 fb[2][4];
      fb[0][0] = *(const bf16x8*)(sIR);
      fb[0][1] = *(const bf16x8*)(sIZ);
      fb[0][2] = *(const bf16x8*)(sHR);
      fb[0][3] = *(const bf16x8*)(sHZ);
      #pragma unroll 1
      for (int kk=0;kk<8;kk++){
        int cur = kk & 1;
        if (kk < 7){
          int nb = (kk+1)*512;
          fb[cur^1][0] = *(const bf16x8*)(sIR + nb);
          fb[cur^1][1] = *(const bf16x8*)(sIZ + nb);
          fb[cur^1][2] = *(const bf16x8*)(sHR + nb);
          fb[cur^1][3] = *(const bf16x8*)(sHZ + nb);
        }
        int ab = aoff + kk*64;
        bf16x8 aE0 = *(const bf16x8*)((char*)emb_s + (ab ^ xr));
        bf16x8 aE1 = *(const bf16x8*)((char*)emb_s + ((ab + 8192) ^ xr));
        bf16x8 aH0 = *(const bf16x8*)((char*)hb_s + (ab ^ xr));
        bf16x8 aH1 = *(const bf16x8*)((char*)hb_s + ((ab + 8192) ^ xr));
        aR[0] = MFMA16(aE0, fb[cur][0], aR[0]);
        aR[1] = MFMA16(aE1, fb[cur][0], aR[1]);
        aZ[0] = MFMA16(aE0, fb[cur][1], aZ[0]);
        aZ[1] = MFMA16(aE1, fb[cur][1], aZ[1]);
        aR[0] = MFMA16(aH0, fb[cur][2], aR[0]);
        aR[1] = MFMA16(aH1, fb[cur][2], aR[1]);
        aZ[0] = MFMA16(aH0, fb[cur][3], aZ[0]);
        aZ[1] = MFMA16(aH1, fb[cur][3], aZ[1]);
      }
    }
    // ---- pass B: XN,HN (2 streams, dbuf) ----
    aXN[0]=(f32x4){0,0,0,0}; aXN[1]=(f32x4){0,0,0,0};
    aHN[0]=(f32x4){0,0,0,0}; aHN[1]=(f32x4){0,0,0,0};
    {
      bf16x8 fb[2][2];
      fb[0][0] = *(const bf16x8*)(sIN);
      fb[0][1] = *(const bf16x8*)(sHN);
      #pragma unroll 1
      for (int kk=0;kk<8;kk++){
        int cur = kk & 1;
        if (kk < 7){
          int nb = (kk+1)*512;
          fb[cur^1][0] = *(const bf16x8*)(sIN + nb);
          fb[cur^1][1] = *(const bf16x8*)(sHN + nb);
        }
        int ab = aoff + kk*64;
        bf16x8 aE0 = *(const bf16x8*)((char*)emb_s + (ab ^ xr));
        bf16x8 aE1 = *(const bf16x8*)((char*)emb_s + ((ab + 8192) ^ xr));
        bf16x8 aH0 = *(const bf16x8*)((char*)hb_s + (ab ^ xr));
        bf16x8 aH1 = *(const bf16x8*)((char*)hb_s + ((ab + 8192) ^ xr));
        aXN[0] = MFMA16(aE0, fb[cur][0], aXN[0]);
        aXN[1] = MFMA16(aE1, fb[cur][0], aXN[1]);
        aHN[0] = MFMA16(aH0, fb[cur][1], aHN[0]);
        aHN[1] = MFMA16(aH1, fb[cur][1], aHN[1]);
      }
    }
    __syncthreads();   // all hb_s reads done
    // ---- gate update (wave-local; lane owns col jcol, rows mt*16+lh*4+r) ----
    #pragma unroll
    for (int mt=0;mt<2;mt++){
      #pragma unroll
      for (int r=0;r<4;r++){
        float rp = aR[mt][r]  + bR;
        float zp = aZ[mt][r]  + bZ;
        float xn = aXN[mt][r] + bXN;
        float hn = aHN[mt][r] + bHN;
        float rg = 1.f/(1.f + __expf(-rp));
        float zg = 1.f/(1.f + __expf(-zp));
        float arg = xn + rg*hn;
        float e2 = __expf(2.f*arg);
        float nv = (e2 - 1.f)/(e2 + 1.f);
        int m = mt*16 + lh*4 + r;
        int byte = (m*512 + jj2) ^ ((m&15)<<4);
        unsigned short* hp = (unsigned short*)((char*)hb_s + byte);
        float hold = bf2f(*hp);
        float hnew = (1.f - zg)*nv + zg*hold;
        *hp = f2bf(hnew);
        if (step == 49){
          int rr = blk*32 + m; int b = rr/24; int nd = 1 + (rr - b*24);
          nemb[(size_t)(b*25+nd)*256 + jcol] = f2bf(hnew);
        }
      }
    }
    __syncthreads();
  }
}

// ---------------- GAT scores + softmax + node0 out + dueling head ----------------
__global__ __launch_bounds__(256) void gat_k(const int* __restrict__ edges,
              const unsigned short* __restrict__ glgr,
              const float* __restrict__ att, const float* __restrict__ gbias,
              const float* __restrict__ hidw, const float* __restrict__ hidb,
              const float* __restrict__ outw, const float* __restrict__ outb,
              const float* __restrict__ advw, const float* __restrict__ advb,
              float* __restrict__ out){
  __shared__ int src_s[125], dst_s[125];
  __shared__ __align__(16) float att_s[1280];
  __shared__ float sc[125][5], al[125][5];
  __shared__ float mx[25][5], dn[25][5];
  __shared__ float g0[256], hh[256];
  __shared__ float adv_s[8], v_s;
  __shared__ int e0[125]; __shared__ int ne0;

  int b = blockIdx.x, t = threadIdx.x;
  if (t < 100){ src_s[t] = edges[b*200 + t]; dst_s[t] = edges[b*200 + 100 + t]; }
  else if (t < 125){ src_s[t] = t - 100; dst_s[t] = t - 100; }
  for (int j = t; j < 1280; j += 256) att_s[j] = att[j];
  __syncthreads();
  if (t == 0){ int c = 0; for (int e=0;e<125;e++) if (dst_s[e]==0) e0[c++]=e; ne0 = c; }
  const unsigned short* gbase = glgr + (size_t)b*25*2560;
  for (int p = t; p < 625; p += 256){
    int e = p/5, h = p - 5*(p/5);
    const unsigned short* glp = gbase + src_s[e]*2560 + h*256;
    const unsigned short* grp = gbase + dst_s[e]*2560 + 1280 + h*256;
    const float* ap = &att_s[h*256];
    float acc = 0.f;
    #pragma unroll 4
    for (int c=0;c<256;c+=8){
      uint4v gu = *(const uint4v*)&glp[c];
      uint4v ru = *(const uint4v*)&grp[c];
      #pragma unroll
      for (int q=0;q<4;q++){
        float s0 = bflo(gu[q]) + bflo(ru[q]);
        float s1 = bfhi(gu[q]) + bfhi(ru[q]);
        s0 = (s0 > 0.f) ? s0 : 0.2f*s0;
        s1 = (s1 > 0.f) ? s1 : 0.2f*s1;
        acc += s0*ap[c+2*q] + s1*ap[c+2*q+1];
      }
    }
    sc[e][h] = acc;
  }
  __syncthreads();
  if (t < 125){
    int j = t/5, h = t - 5*(t/5);
    float m = -1e30f;
    for (int e=0;e<125;e++) if (dst_s[e]==j) m = fmaxf(m, sc[e][h]);
    float d = 0.f;
    for (int e=0;e<125;e++) if (dst_s[e]==j) d += __expf(sc[e][h]-m);
    mx[j][h] = m; dn[j][h] = d;
  }
  __syncthreads();
  for (int p = t; p < 625; p += 256){
    int e = p/5, h = p - 5*(p/5);
    int dd = dst_s[e];
    al[e][h] = __expf(sc[e][h] - mx[dd][h]) / dn[dd][h];
  }
  __syncthreads();
  if (t < 101){
    out[2048 + b*101 + t] = (al[t][0]+al[t][1]+al[t][2]+al[t][3]+al[t][4])*0.2f;
  }
  {
    float acc = 0.f;
    for (int x=0;x<ne0;x++){
      int e = e0[x]; int s = src_s[e];
      const unsigned short* glp = gbase + s*2560 + t;
      #pragma unroll
      for (int h=0;h<5;h++) acc += al[e][h]*bf2f(glp[h*256]);
    }
    g0[t] = acc*0.2f + gbias[t];
  }
  __syncthreads();
  {
    float acc = hidb[t];
    for (int k=0;k<256;k++) acc += g0[k]*hidw[k*256+t];
    hh[t] = fmaxf(acc, 0.f);
  }
  __syncthreads();
  if (t < 8){
    float acc = advb[t];
    for (int k=0;k<256;k++) acc += hh[k]*advw[k*8+t];
    adv_s[t] = acc;
  } else if (t == 8){
    float acc = outb[0];
    for (int k=0;k<256;k++) acc += hh[k]*outw[k];
    v_s = acc;
  }
  __syncthreads();
  if (t < 8){
    float m = adv_s[0]+adv_s[1]+adv_s[2]+adv_s[3]+adv_s[4]+adv_s[5]+adv_s[6]+adv_s[7];
    out[b*8+t] = v_s + adv_s[t] - m*0.125f;
  }
}

extern "C" void kernel_launch(void* const* d_in, const int* in_sizes, int n_in,
                              void* d_out, int out_size, void* d_ws, size_t ws_size,
                              hipStream_t stream){
  const float* obs     = (const float*)d_in[0];
  const float* obs_map = (const float*)d_in[1];
  const int*   edges   = (const int*)d_in[2];
  const float* mlp_w = (const float*)d_in[4];
  const float* mlp_b = (const float*)d_in[5];
  const float* c1w = (const float*)d_in[6];  const float* c1b = (const float*)d_in[7];
  const float* c2w = (const float*)d_in[8];  const float* c2b = (const float*)d_in[9];
  const float* c3w = (const float*)d_in[10]; const float* c3b = (const float*)d_in[11];
  const float* fcw = (const float*)d_in[12]; const float* fcb = (const float*)d_in[13];
  const float* wih = (const float*)d_in[14]; const float* whh = (const float*)d_in[15];
  const float* bih = (const float*)d_in[16]; const float* bhh = (const float*)d_in[17];
  const float* gwl = (const float*)d_in[18]; const float* gbl = (const float*)d_in[19];
  const float* gwr = (const float*)d_in[20]; const float* gbr = (const float*)d_in[21];
  const float* gatt = (const float*)d_in[22]; const float* gbias = (const float*)d_in[23];
  const float* hidw = (const float*)d_in[24]; const float* hidb = (const float*)d_in[25];
  const float* outw = (const float*)d_in[26]; const float* outb = (const float*)d_in[27];
  const float* advw = (const float*)d_in[28]; const float* advb = (const float*)d_in[29];
  float* out = (float*)d_out;
  char* ws = (char*)d_ws;

  // workspace layout (conv buffers aliased under glgr; consumed before glgr write)
  unsigned short* c1o  = (unsigned short*)(ws + 0);          // 6,553,600 B
  unsigned short* c2o  = (unsigned short*)(ws + 6553600);    // 2,654,208 B
  unsigned short* c3o  = (unsigned short*)(ws + 9207808);    // 1,605,632 B
  unsigned short* glgr = (unsigned short*)(ws + 0);          // 32,768,000 B
  size_t o = 32768000;
  unsigned short* nemb  = (unsigned short*)(ws + o); o += 3276800;
  unsigned short* wfrag = (unsigned short*)(ws + o); o += 786432;
  unsigned short* wlrT  = (unsigned short*)(ws + o); o += 1310720;
  unsigned short* fcwT  = (unsigned short*)(ws + o); o += 1605632;
  float* blbr           = (float*)(ws + o); o += 10240;

  prep_k<<<7242, 256, 0, stream>>>(wih, whh, gwl, gwr, gbl, gbr, fcw, wfrag, wlrT, fcwT, blbr);
  conv1_k<<<1024, 256, 0, stream>>>(obs_map, c1w, c1b, c1o);
  conv2_k<<<1024, 256, 0, stream>>>(c1o, c2w, c2b, c2o);
  conv3_k<<<1024, 256, 0, stream>>>(c2o, c3w, c3b, c3o);
  gemm_k<<<16, 256, 0, stream>>>(c3o, fcwT, fcb, nemb, 3136, 256, 25, 1, 4);      // FC -> node 0
  gru_k<<<192, 1024, 0, stream>>>(obs, mlp_w, mlp_b, wfrag, bih, bhh, nemb);      // nodes 1..24
  gemm_k<<<4000, 256, 0, stream>>>(nemb, wlrT, blbr, glgr, 256, 2560, 1, 0, 40);  // gl|gr
  gat_k<<<256, 256, 0, stream>>>(edges, glgr, gatt, gbias, hidw, hidb, outw, outb, advw, advb, out);
}

// Round 4
// 1006.171 us; speedup vs baseline: 45.4910x; 45.4910x over previous
//
#include <hip/hip_runtime.h>
#include <cstdint>

typedef __attribute__((ext_vector_type(8))) __bf16 bf16x8;
typedef __attribute__((ext_vector_type(4))) float f32x4;
typedef __attribute__((ext_vector_type(4))) unsigned int uint4v;
typedef __attribute__((ext_vector_type(4))) float float4v;

__device__ __forceinline__ unsigned short f2bf(float x){
  union { float f; unsigned u; } v; v.f = x;
  unsigned r = v.u + 0x7FFFu + ((v.u >> 16) & 1u);
  return (unsigned short)(r >> 16);
}
__device__ __forceinline__ float bf2f(unsigned short h){
  union { unsigned u; float f; } v; v.u = ((unsigned)h) << 16;
  return v.f;
}
__device__ __forceinline__ float bflo(unsigned u){
  union { unsigned x; float f; } v; v.x = u << 16; return v.f;
}
__device__ __forceinline__ float bfhi(unsigned u){
  union { unsigned x; float f; } v; v.x = u & 0xFFFF0000u; return v.f;
}
__device__ __forceinline__ f32x4 MFMA16(bf16x8 a, bf16x8 b, f32x4 c){
  return __builtin_amdgcn_mfma_f32_16x16x32_bf16(a, b, c, 0, 0, 0);
}

// ---------------- prep: bf16 conversions + transposes + GRU weight frag layout ----
// wfrag layout: [mg(6)=mat*3+gate][ct(16)][kk(8)][lane(64)][e(8)] bf16
//   element = W_mat[n*256+k], n = gate*256 + ct*16 + (lane&15), k = kk*32 + (lane>>4)*8 + e
__global__ __launch_bounds__(256) void prep_k(
    const float* __restrict__ wih, const float* __restrict__ whh,
    const float* __restrict__ wl, const float* __restrict__ wr,
    const float* __restrict__ bl, const float* __restrict__ br,
    const float* __restrict__ fcw,
    unsigned short* __restrict__ wfrag,
    unsigned short* __restrict__ wlrT, unsigned short* __restrict__ fcwT,
    float* __restrict__ blbr){
  int i = blockIdx.x*256 + threadIdx.x;
  if (i < 393216){
    int mg = i >> 16;            // 0..5 = mat*3+gate
    int rem = i & 65535;
    int ct = rem >> 12;
    int r3 = rem & 4095;
    int kk = r3 >> 9;
    int r4 = r3 & 511;
    int l = r4 >> 3, e = r4 & 7;
    int mat = mg / 3, g = mg - 3*(mg/3);
    int n = g*256 + ct*16 + (l & 15);
    int k = kk*32 + (l >> 4)*8 + e;
    float v = mat ? whh[n*256 + k] : wih[n*256 + k];
    wfrag[i] = f2bf(v);
    return;
  }
  i -= 393216;
  if (i < 655360){
    int n = i >> 8, k = i & 255;
    float v = (n < 1280) ? wl[k*1280 + n] : wr[k*1280 + (n-1280)];
    wlrT[i] = f2bf(v); return;
  }
  i -= 655360;
  if (i < 802816){
    int n = i / 3136, k = i - n*3136;
    fcwT[i] = f2bf(fcw[k*256 + n]); return;
  }
  i -= 802816;
  if (i < 2560){
    blbr[i] = (i < 1280) ? bl[i] : br[i-1280];
  }
}

// ---------------- conv1: [256,3,84,84] -> bf16 [256,32,20,20], s=4 k=8, relu ----
__global__ __launch_bounds__(256) void conv1_k(const float* __restrict__ in,
              const float* __restrict__ w, const float* __restrict__ bias,
              unsigned short* __restrict__ out){
  __shared__ float in_s[3][24][84];
  __shared__ float w_s[32][3][8][8];
  __shared__ float b_s[32];
  int bid = blockIdx.x; int b = bid >> 2, q = bid & 3;
  int t = threadIdx.x;
  for (int idx = t; idx < 3*24*84; idx += 256){
    int ic = idx / (24*84); int rem = idx - ic*(24*84);
    int iy = rem / 84, ix = rem - iy*84;
    in_s[ic][iy][ix] = in[((size_t)(b*3+ic)*84 + (q*20 + iy))*84 + ix];
  }
  for (int idx = t; idx < 32*192; idx += 256) ((float*)w_s)[idx] = w[idx];
  if (t < 32) b_s[t] = bias[t];
  __syncthreads();
  for (int p = t; p < 800; p += 256){
    int oc = p / 25; int rem = p - oc*25;
    int oy = rem / 5, og = rem - oy*5;
    float a0=b_s[oc],a1=b_s[oc],a2=b_s[oc],a3=b_s[oc];
    #pragma unroll
    for (int ic=0;ic<3;ic++){
      #pragma unroll
      for (int ky=0;ky<8;ky++){
        const float* row = &in_s[ic][oy*4+ky][og*16];
        float s[20];
        #pragma unroll
        for (int cc=0;cc<20;cc++) s[cc]=row[cc];
        const float* wp = &w_s[oc][ic][ky][0];
        #pragma unroll
        for (int kx=0;kx<8;kx++){
          float wv = wp[kx];
          a0 += s[kx]*wv; a1 += s[4+kx]*wv; a2 += s[8+kx]*wv; a3 += s[12+kx]*wv;
        }
      }
    }
    size_t ob = ((size_t)(b*32+oc)*20 + (q*5+oy))*20 + og*4;
    out[ob+0]=f2bf(fmaxf(a0,0.f)); out[ob+1]=f2bf(fmaxf(a1,0.f));
    out[ob+2]=f2bf(fmaxf(a2,0.f)); out[ob+3]=f2bf(fmaxf(a3,0.f));
  }
}

// ---------------- conv2: bf16 [256,32,20,20] -> bf16 [256,64,9,9], s=2 k=4 ----
__global__ __launch_bounds__(256) void conv2_k(const unsigned short* __restrict__ in,
              const float* __restrict__ w, const float* __restrict__ bias,
              unsigned short* __restrict__ out){
  __shared__ unsigned short in_s[32][20][20];
  __shared__ float w_s[16][32][4][4];
  __shared__ float b_s[16];
  int bid = blockIdx.x; int b = bid >> 2, h = bid & 3;
  int t = threadIdx.x;
  for (int idx = t; idx < 32*400; idx += 256) ((unsigned short*)in_s)[idx] = in[(size_t)b*12800 + idx];
  for (int idx = t; idx < 16*512; idx += 256) ((float*)w_s)[idx] = w[h*8192 + idx];
  if (t < 16) b_s[t] = bias[h*16 + t];
  __syncthreads();
  for (int p = t; p < 432; p += 256){
    int ocl = p / 27; int rem = p - ocl*27;
    int oy = rem / 3, og = rem - oy*3;
    float a0=b_s[ocl],a1=b_s[ocl],a2=b_s[ocl];
    #pragma unroll 4
    for (int ic=0;ic<32;ic++){
      #pragma unroll
      for (int ky=0;ky<4;ky++){
        const unsigned short* row = &in_s[ic][oy*2+ky][og*6];
        float s[8];
        #pragma unroll
        for (int cc=0;cc<8;cc++) s[cc]=bf2f(row[cc]);
        const float* wp = &w_s[ocl][ic][ky][0];
        #pragma unroll
        for (int kx=0;kx<4;kx++){
          float wv = wp[kx];
          a0 += s[kx]*wv; a1 += s[2+kx]*wv; a2 += s[4+kx]*wv;
        }
      }
    }
    size_t ob = ((size_t)(b*64 + h*16+ocl)*9 + oy)*9 + og*3;
    out[ob+0]=f2bf(fmaxf(a0,0.f)); out[ob+1]=f2bf(fmaxf(a1,0.f)); out[ob+2]=f2bf(fmaxf(a2,0.f));
  }
}

// ---------------- conv3: bf16 [256,64,9,9] -> bf16 [256,3136] (flat NCHW), s=1 k=3 ----
__global__ __launch_bounds__(256) void conv3_k(const unsigned short* __restrict__ in,
              const float* __restrict__ w, const float* __restrict__ bias,
              unsigned short* __restrict__ out){
  __shared__ unsigned short in_s[64][9][9];
  __shared__ float w_s[16][64][3][3];
  __shared__ float b_s[16];
  int bid = blockIdx.x; int b = bid >> 2, h = bid & 3;
  int t = threadIdx.x;
  for (int idx = t; idx < 64*81; idx += 256) ((unsigned short*)in_s)[idx] = in[(size_t)b*5184 + idx];
  for (int idx = t; idx < 16*576; idx += 256) ((float*)w_s)[idx] = w[h*9216 + idx];
  if (t < 16) b_s[t] = bias[h*16 + t];
  __syncthreads();
  for (int p = t; p < 224; p += 256){
    int ocl = p / 14; int rem = p - ocl*14;
    int oy = rem >> 1, og = rem & 1;
    int ox0 = og*4; int nx = og ? 3 : 4;
    float a[4]; a[0]=a[1]=a[2]=a[3]=b_s[ocl];
    for (int ic=0;ic<64;ic++){
      #pragma unroll
      for (int ky=0;ky<3;ky++){
        const unsigned short* row = &in_s[ic][oy+ky][ox0];
        float s[6];
        #pragma unroll
        for (int cc=0;cc<6;cc++) s[cc] = (ox0+cc < 9) ? bf2f(row[cc]) : 0.f;
        const float* wp = &w_s[ocl][ic][ky][0];
        #pragma unroll
        for (int kx=0;kx<3;kx++){
          float wv = wp[kx];
          #pragma unroll
          for (int jj=0;jj<4;jj++) a[jj] += s[jj+kx]*wv;
        }
      }
    }
    size_t ob = (size_t)b*3136 + (h*16+ocl)*49 + oy*7 + ox0;
    #pragma unroll
    for (int jj=0;jj<4;jj++) if (jj < nx) out[ob+jj] = f2bf(fmaxf(a[jj],0.f));
  }
}

// ---------------- generic MFMA GEMM: C[m,n] = act(A[m,:]·B[n,:] + bias[n]) ----
__global__ __launch_bounds__(256) void gemm_k(const unsigned short* __restrict__ A,
              const unsigned short* __restrict__ B, const float* __restrict__ bias,
              unsigned short* __restrict__ C, int K, int ldc, int rowmul, int relu, int Nblk){
  __shared__ __align__(16) unsigned short As[64*32];
  __shared__ __align__(16) unsigned short Bs[64*32];
  int bid = blockIdx.x;
  int nb = bid % Nblk, mb = bid / Nblk;
  int t = threadIdx.x;
  int w = t >> 6, l = t & 63, lr = l & 15, lh = l >> 4;
  int sr = t >> 2, sq = t & 3;
  f32x4 acc[4];
  #pragma unroll
  for (int i=0;i<4;i++) acc[i] = (f32x4){0.f,0.f,0.f,0.f};
  int nkk = K >> 5;
  const size_t a_row = (size_t)(mb*64 + sr)*K;
  const size_t b_row = (size_t)(nb*64 + sr)*K;
  for (int kk=0;kk<nkk;kk++){
    uint4v av = *(const uint4v*)&A[a_row + kk*32 + sq*8];
    uint4v bv = *(const uint4v*)&B[b_row + kk*32 + sq*8];
    __syncthreads();
    *(uint4v*)((char*)As + ((sr*64 + sq*16) ^ ((sr&3)<<4))) = av;
    *(uint4v*)((char*)Bs + ((sr*64 + sq*16) ^ ((sr&3)<<4))) = bv;
    __syncthreads();
    int brow = w*16 + lr;
    bf16x8 bfr = *(const bf16x8*)((char*)Bs + ((brow*64 + lh*16) ^ ((brow&3)<<4)));
    #pragma unroll
    for (int mt=0;mt<4;mt++){
      int arow = mt*16 + lr;
      bf16x8 afr = *(const bf16x8*)((char*)As + ((arow*64 + lh*16) ^ ((arow&3)<<4)));
      acc[mt] = MFMA16(afr, bfr, acc[mt]);
    }
  }
  int col = nb*64 + w*16 + lr;
  float bn = bias[col];
  #pragma unroll
  for (int mt=0;mt<4;mt++){
    #pragma unroll
    for (int r=0;r<4;r++){
      int row = mb*64 + mt*16 + lh*4 + r;
      float v = acc[mt][r] + bn;
      if (relu) v = fmaxf(v, 0.f);
      C[(size_t)row*rowmul*ldc + col] = f2bf(v);
    }
  }
}

// ---------------- fused MLP+GRU persistent kernel (v4: direct loads, no reg arrays) --
// 192 blocks x 1024 threads (16 waves, 4/SIMD); block owns 32 rows; wave owns 16 h-cols.
__global__ __launch_bounds__(1024, 4) void gru_k(const float* __restrict__ obs,
              const float* __restrict__ mlpw, const float* __restrict__ mlpb,
              const unsigned short* __restrict__ wfrag,
              const float* __restrict__ bih, const float* __restrict__ bhh,
              unsigned short* __restrict__ nemb){
  __shared__ __align__(16) float obs_s[32][16];
  __shared__ __align__(16) unsigned short mlp_s[16*256];
  __shared__ __align__(16) float mlpb_s[256];
  __shared__ __align__(16) unsigned short emb_s[32*256];  // swizzled ^(m&15)<<4
  __shared__ __align__(16) unsigned short hb_s[32*256];   // swizzled ^(m&15)<<4

  const int t = threadIdx.x, blk = blockIdx.x;
  for (int j = t; j < 4096; j += 1024) mlp_s[j] = f2bf(mlpw[j]);
  if (t < 256) mlpb_s[t] = mlpb[t];
  for (int j = t; j < 8192; j += 1024) hb_s[j] = 0;

  const int w = t >> 6, l = t & 63, lr = l & 15, lh = l >> 4;
  const int jcol = w*16 + lr;            // h/gate column this lane produces
  const float bR  = bih[jcol]     + bhh[jcol];
  const float bZ  = bih[256+jcol] + bhh[256+jcol];
  const float bXN = bih[512+jcol];
  const float bHN = bhh[512+jcol];

  // per-lane weight base; streams at +mg*65536 elements (mg: 0=ihR 1=ihZ 2=ihN 3=hhR 4=hhZ 5=hhN)
  const unsigned short* wb = wfrag + w*4096 + l*8;

  const int em = t >> 5, en0 = (t & 31) << 3;   // MLP: row, col0 (8 cols/thread)

  const int orow = t >> 4, oc = t & 15;          // obs stage (t<512)
  int rrL = blk*32 + orow; int bL = rrL/24, ndL = 1 + (rrL - bL*24);
  const float* obase = obs + (size_t)(bL*25 + ndL)*800 + oc;

  const int aoff = lr*512 + lh*16;   // A-frag base byte (row=lr)
  const int xr = lr << 4;            // swizzle
  const int jj2 = jcol*2;

  __syncthreads();

  for (int step=0; step<50; step++){
    if (t < 512) obs_s[orow][oc] = obase[step*16];
    __syncthreads();
    // ---- MLP emb: thread -> 8 cols of one row ----
    {
      float acc[8];
      #pragma unroll
      for (int q=0;q<8;q++) acc[q] = mlpb_s[en0+q];
      #pragma unroll
      for (int k=0;k<16;k++){
        float o = obs_s[em][k];
        uint4v wv = *(const uint4v*)&mlp_s[k*256 + en0];
        acc[0] += o*bflo(wv[0]); acc[1] += o*bfhi(wv[0]);
        acc[2] += o*bflo(wv[1]); acc[3] += o*bfhi(wv[1]);
        acc[4] += o*bflo(wv[2]); acc[5] += o*bfhi(wv[2]);
        acc[6] += o*bflo(wv[3]); acc[7] += o*bfhi(wv[3]);
      }
      uint4v pk;
      #pragma unroll
      for (int q=0;q<4;q++){
        float x0 = fmaxf(acc[2*q],0.f), x1 = fmaxf(acc[2*q+1],0.f);
        pk[q] = (unsigned)f2bf(x0) | ((unsigned)f2bf(x1) << 16);
      }
      *(uint4v*)((char*)emb_s + ((em*512 + (en0<<1)) ^ ((em&15)<<4))) = pk;
    }
    __syncthreads();
    // ---- MFMA: 6 direct weight loads per kk (L2-hit), 4 LDS A-frags, 12 MFMAs ----
    f32x4 aR0=(f32x4){0,0,0,0}, aR1=(f32x4){0,0,0,0};
    f32x4 aZ0=(f32x4){0,0,0,0}, aZ1=(f32x4){0,0,0,0};
    f32x4 aN0=(f32x4){0,0,0,0}, aN1=(f32x4){0,0,0,0};   // xn part
    f32x4 aM0=(f32x4){0,0,0,0}, aM1=(f32x4){0,0,0,0};   // hn part
    #pragma unroll 2
    for (int kk=0;kk<8;kk++){
      const unsigned short* wk = wb + kk*512;
      bf16x8 bIR = *(const bf16x8*)(wk);
      bf16x8 bIZ = *(const bf16x8*)(wk + 65536);
      bf16x8 bIN = *(const bf16x8*)(wk + 131072);
      bf16x8 bHR = *(const bf16x8*)(wk + 196608);
      bf16x8 bHZ = *(const bf16x8*)(wk + 262144);
      bf16x8 bHN = *(const bf16x8*)(wk + 327680);
      int ab = aoff + kk*64;
      bf16x8 aE0 = *(const bf16x8*)((char*)emb_s + (ab ^ xr));
      bf16x8 aE1 = *(const bf16x8*)((char*)emb_s + ((ab + 8192) ^ xr));
      bf16x8 aH0 = *(const bf16x8*)((char*)hb_s + (ab ^ xr));
      bf16x8 aH1 = *(const bf16x8*)((char*)hb_s + ((ab + 8192) ^ xr));
      aR0 = MFMA16(aE0, bIR, aR0);  aR0 = MFMA16(aH0, bHR, aR0);
      aR1 = MFMA16(aE1, bIR, aR1);  aR1 = MFMA16(aH1, bHR, aR1);
      aZ0 = MFMA16(aE0, bIZ, aZ0);  aZ0 = MFMA16(aH0, bHZ, aZ0);
      aZ1 = MFMA16(aE1, bIZ, aZ1);  aZ1 = MFMA16(aH1, bHZ, aZ1);
      aN0 = MFMA16(aE0, bIN, aN0);  aN1 = MFMA16(aE1, bIN, aN1);
      aM0 = MFMA16(aH0, bHN, aM0);  aM1 = MFMA16(aH1, bHN, aM1);
    }
    __syncthreads();   // all hb_s reads done
    // ---- gate update (wave-local; lane owns col jcol, rows mt*16+lh*4+r) ----
    #pragma unroll
    for (int mt=0;mt<2;mt++){
      f32x4 vR = mt ? aR1 : aR0;
      f32x4 vZ = mt ? aZ1 : aZ0;
      f32x4 vN = mt ? aN1 : aN0;
      f32x4 vM = mt ? aM1 : aM0;
      #pragma unroll
      for (int r=0;r<4;r++){
        float rp = vR[r] + bR;
        float zp = vZ[r] + bZ;
        float xn = vN[r] + bXN;
        float hn = vM[r] + bHN;
        float rg = 1.f/(1.f + __expf(-rp));
        float zg = 1.f/(1.f + __expf(-zp));
        float arg = xn + rg*hn;
        float e2 = __expf(2.f*arg);
        float nv = (e2 - 1.f)/(e2 + 1.f);
        int m = mt*16 + lh*4 + r;
        int byte = (m*512 + jj2) ^ ((m&15)<<4);
        unsigned short* hp = (unsigned short*)((char*)hb_s + byte);
        float hold = bf2f(*hp);
        float hnew = (1.f - zg)*nv + zg*hold;
        *hp = f2bf(hnew);
        if (step == 49){
          int rr = blk*32 + m; int b = rr/24; int nd = 1 + (rr - b*24);
          nemb[(size_t)(b*25+nd)*256 + jcol] = f2bf(hnew);
        }
      }
    }
    __syncthreads();
  }
}

// ---------------- GAT scores + softmax + node0 out + dueling head ----------------
__global__ __launch_bounds__(256) void gat_k(const int* __restrict__ edges,
              const unsigned short* __restrict__ glgr,
              const float* __restrict__ att, const float* __restrict__ gbias,
              const float* __restrict__ hidw, const float* __restrict__ hidb,
              const float* __restrict__ outw, const float* __restrict__ outb,
              const float* __restrict__ advw, const float* __restrict__ advb,
              float* __restrict__ out){
  __shared__ int src_s[125], dst_s[125];
  __shared__ __align__(16) float att_s[1280];
  __shared__ float sc[125][5], al[125][5];
  __shared__ float mx[25][5], dn[25][5];
  __shared__ float g0[256], hh[256];
  __shared__ float adv_s[8], v_s;
  __shared__ int e0[125]; __shared__ int ne0;

  int b = blockIdx.x, t = threadIdx.x;
  if (t < 100){ src_s[t] = edges[b*200 + t]; dst_s[t] = edges[b*200 + 100 + t]; }
  else if (t < 125){ src_s[t] = t - 100; dst_s[t] = t - 100; }
  for (int j = t; j < 1280; j += 256) att_s[j] = att[j];
  __syncthreads();
  if (t == 0){ int c = 0; for (int e=0;e<125;e++) if (dst_s[e]==0) e0[c++]=e; ne0 = c; }
  const unsigned short* gbase = glgr + (size_t)b*25*2560;
  for (int p = t; p < 625; p += 256){
    int e = p/5, h = p - 5*(p/5);
    const unsigned short* glp = gbase + src_s[e]*2560 + h*256;
    const unsigned short* grp = gbase + dst_s[e]*2560 + 1280 + h*256;
    const float* ap = &att_s[h*256];
    float acc = 0.f;
    #pragma unroll 4
    for (int c=0;c<256;c+=8){
      uint4v gu = *(const uint4v*)&glp[c];
      uint4v ru = *(const uint4v*)&grp[c];
      #pragma unroll
      for (int q=0;q<4;q++){
        float s0 = bflo(gu[q]) + bflo(ru[q]);
        float s1 = bfhi(gu[q]) + bfhi(ru[q]);
        s0 = (s0 > 0.f) ? s0 : 0.2f*s0;
        s1 = (s1 > 0.f) ? s1 : 0.2f*s1;
        acc += s0*ap[c+2*q] + s1*ap[c+2*q+1];
      }
    }
    sc[e][h] = acc;
  }
  __syncthreads();
  if (t < 125){
    int j = t/5, h = t - 5*(t/5);
    float m = -1e30f;
    for (int e=0;e<125;e++) if (dst_s[e]==j) m = fmaxf(m, sc[e][h]);
    float d = 0.f;
    for (int e=0;e<125;e++) if (dst_s[e]==j) d += __expf(sc[e][h]-m);
    mx[j][h] = m; dn[j][h] = d;
  }
  __syncthreads();
  for (int p = t; p < 625; p += 256){
    int e = p/5, h = p - 5*(p/5);
    int dd = dst_s[e];
    al[e][h] = __expf(sc[e][h] - mx[dd][h]) / dn[dd][h];
  }
  __syncthreads();
  if (t < 101){
    out[2048 + b*101 + t] = (al[t][0]+al[t][1]+al[t][2]+al[t][3]+al[t][4])*0.2f;
  }
  {
    float acc = 0.f;
    for (int x=0;x<ne0;x++){
      int e = e0[x]; int s = src_s[e];
      const unsigned short* glp = gbase + s*2560 + t;
      #pragma unroll
      for (int h=0;h<5;h++) acc += al[e][h]*bf2f(glp[h*256]);
    }
    g0[t] = acc*0.2f + gbias[t];
  }
  __syncthreads();
  {
    float acc = hidb[t];
    for (int k=0;k<256;k++) acc += g0[k]*hidw[k*256+t];
    hh[t] = fmaxf(acc, 0.f);
  }
  __syncthreads();
  if (t < 8){
    float acc = advb[t];
    for (int k=0;k<256;k++) acc += hh[k]*advw[k*8+t];
    adv_s[t] = acc;
  } else if (t == 8){
    float acc = outb[0];
    for (int k=0;k<256;k++) acc += hh[k]*outw[k];
    v_s = acc;
  }
  __syncthreads();
  if (t < 8){
    float m = adv_s[0]+adv_s[1]+adv_s[2]+adv_s[3]+adv_s[4]+adv_s[5]+adv_s[6]+adv_s[7];
    out[b*8+t] = v_s + adv_s[t] - m*0.125f;
  }
}

extern "C" void kernel_launch(void* const* d_in, const int* in_sizes, int n_in,
                              void* d_out, int out_size, void* d_ws, size_t ws_size,
                              hipStream_t stream){
  const float* obs     = (const float*)d_in[0];
  const float* obs_map = (const float*)d_in[1];
  const int*   edges   = (const int*)d_in[2];
  const float* mlp_w = (const float*)d_in[4];
  const float* mlp_b = (const float*)d_in[5];
  const float* c1w = (const float*)d_in[6];  const float* c1b = (const float*)d_in[7];
  const float* c2w = (const float*)d_in[8];  const float* c2b = (const float*)d_in[9];
  const float* c3w = (const float*)d_in[10]; const float* c3b = (const float*)d_in[11];
  const float* fcw = (const float*)d_in[12]; const float* fcb = (const float*)d_in[13];
  const float* wih = (const float*)d_in[14]; const float* whh = (const float*)d_in[15];
  const float* bih = (const float*)d_in[16]; const float* bhh = (const float*)d_in[17];
  const float* gwl = (const float*)d_in[18]; const float* gbl = (const float*)d_in[19];
  const float* gwr = (const float*)d_in[20]; const float* gbr = (const float*)d_in[21];
  const float* gatt = (const float*)d_in[22]; const float* gbias = (const float*)d_in[23];
  const float* hidw = (const float*)d_in[24]; const float* hidb = (const float*)d_in[25];
  const float* outw = (const float*)d_in[26]; const float* outb = (const float*)d_in[27];
  const float* advw = (const float*)d_in[28]; const float* advb = (const float*)d_in[29];
  float* out = (float*)d_out;
  char* ws = (char*)d_ws;

  // workspace layout (conv buffers aliased under glgr; consumed before glgr write)
  unsigned short* c1o  = (unsigned short*)(ws + 0);          // 6,553,600 B
  unsigned short* c2o  = (unsigned short*)(ws + 6553600);    // 2,654,208 B
  unsigned short* c3o  = (unsigned short*)(ws + 9207808);    // 1,605,632 B
  unsigned short* glgr = (unsigned short*)(ws + 0);          // 32,768,000 B
  size_t o = 32768000;
  unsigned short* nemb  = (unsigned short*)(ws + o); o += 3276800;
  unsigned short* wfrag = (unsigned short*)(ws + o); o += 786432;
  unsigned short* wlrT  = (unsigned short*)(ws + o); o += 1310720;
  unsigned short* fcwT  = (unsigned short*)(ws + o); o += 1605632;
  float* blbr           = (float*)(ws + o); o += 10240;

  prep_k<<<7242, 256, 0, stream>>>(wih, whh, gwl, gwr, gbl, gbr, fcw, wfrag, wlrT, fcwT, blbr);
  conv1_k<<<1024, 256, 0, stream>>>(obs_map, c1w, c1b, c1o);
  conv2_k<<<1024, 256, 0, stream>>>(c1o, c2w, c2b, c2o);
  conv3_k<<<1024, 256, 0, stream>>>(c2o, c3w, c3b, c3o);
  gemm_k<<<16, 256, 0, stream>>>(c3o, fcwT, fcb, nemb, 3136, 256, 25, 1, 4);      // FC -> node 0
  gru_k<<<192, 1024, 0, stream>>>(obs, mlp_w, mlp_b, wfrag, bih, bhh, nemb);      // nodes 1..24
  gemm_k<<<4000, 256, 0, stream>>>(nemb, wlrT, blbr, glgr, 256, 2560, 1, 0, 40);  // gl|gr
  gat_k<<<256, 256, 0, stream>>>(edges, glgr, gatt, gbias, hidw, hidb, outw, outb, advw, advb, out);
}